// Round 6
// baseline (421.217 us; speedup 1.0000x reference)
//
#include <hip/hip_runtime.h>
#include <hip/hip_cooperative_groups.h>

// NetVLAD fp32, N=64 HW=1024 D=512 K=512->K=64. bf16 MFMA.
// R6: single cooperative kernel, 512 blocks x 256 thr, 4 phases:
//   P0: W->wt transpose + zero a_sum/ssq
//   PA: assign GEMM + softmax -> at[k][hw], xt[d][hw] bf16, a_sum
//   PB: v = xt @ at^T (BK=128) + a_sum*C -> out, atomic ssq
//   PC: intra+global L2 scale in place
// grid.sync() between phases; __launch_bounds__(256,2) guarantees 2 blk/CU.

#define EPSF 1e-12f

namespace cg = cooperative_groups;

typedef short bf16x8 __attribute__((ext_vector_type(8)));
typedef float f32x16 __attribute__((ext_vector_type(16)));

__device__ inline unsigned short f2bf_rne(float f) {
  union { float f; unsigned u; } v; v.f = f;
  unsigned u = v.u;
  unsigned r = u + 0x7fffu + ((u >> 16) & 1u);
  return (unsigned short)(r >> 16);
}
__device__ inline unsigned pk2(float a, float b) {
#if __has_builtin(__builtin_amdgcn_cvt_pk_bf16_f32)
  auto r = __builtin_amdgcn_cvt_pk_bf16_f32(a, b);
  return __builtin_bit_cast(unsigned, r);
#else
  return (unsigned)f2bf_rne(a) | ((unsigned)f2bf_rne(b) << 16);
#endif
}

__global__ __launch_bounds__(256, 2) void mega(
    const float* __restrict__ x, const float* __restrict__ Wm,
    const float* __restrict__ b, const float* __restrict__ C,
    float* __restrict__ out,
    unsigned short* __restrict__ at, unsigned short* __restrict__ xt,
    unsigned short* __restrict__ wt, float* __restrict__ a_sum,
    float* __restrict__ ssq) {
  cg::grid_group grid = cg::this_grid();
  __shared__ char smem[34816];
  const int t = threadIdx.x;
  const int bid = blockIdx.x;
  const int w = t >> 6, lane = t & 63, l31 = lane & 31, h = lane >> 5;

  // ---------------- P0: wt transpose (blocks 0-7), zero stats (8-15) -------
  if (bid < 8) {
    float (*tile)[65] = (float(*)[65])smem;
    int col = (t & 15) * 4, rbase = t >> 4;
#pragma unroll
    for (int r = 0; r < 4; ++r) {
      int row = rbase + 16 * r;
      *(float4*)&tile[row][col] =
          *(const float4*)&Wm[(size_t)(bid * 64 + row) * 64 + col];
    }
    __syncthreads();
    int k = t >> 2, seg = (t & 3) * 16;
    size_t o = (size_t)k * 512 + bid * 64 + seg;
#pragma unroll
    for (int j = 0; j < 16; j += 2)
      *(unsigned*)&wt[o + j] = pk2(tile[seg + j][k], tile[seg + j + 1][k]);
  } else if (bid < 16) {
    float4 z = {0.f, 0.f, 0.f, 0.f};
    *(float4*)&a_sum[(size_t)(bid - 8) * 1024 + t * 4] = z;  // covers a_sum+ssq
  }
  grid.sync();

  // ---------------- PA: assign GEMM + softmax -> at, xt, a_sum -------------
  {
    unsigned short (*xs)[72] = (unsigned short(*)[72])smem;            // 128 rows
    unsigned short (*ws)[72] = (unsigned short(*)[72])(smem + 128 * 72 * 2);
    const int p0 = bid * 128;
    const int n = p0 >> 10;
    const int hwbase = p0 & 1023;
    const int q8 = (t >> 4) * 8, c4 = (t & 15) * 4;  // x stage map
    const int wk = t >> 2, wseg = (t & 3) * 16;      // W stage map

    float4 px[8];
    uint4 pw0, pw1;
#pragma unroll
    for (int j = 0; j < 8; ++j)
      px[j] = *(const float4*)&x[(size_t)(p0 + q8 + j) * 512 + c4];
    pw0 = *(const uint4*)&wt[(size_t)wk * 512 + wseg];
    pw1 = *(const uint4*)&wt[(size_t)wk * 512 + wseg + 8];

    f32x16 acc0, acc1;
#pragma unroll
    for (int i = 0; i < 16; ++i) { acc0[i] = 0.f; acc1[i] = 0.f; }

    for (int c = 0; c < 8; ++c) {
      const int dc = c * 64;
      __syncthreads();
#pragma unroll
      for (int j = 0; j < 8; ++j) {
        uint2 ph;
        ph.x = pk2(px[j].x, px[j].y);
        ph.y = pk2(px[j].z, px[j].w);
        *(uint2*)&xs[q8 + j][c4] = ph;
      }
      *(uint4*)&ws[wk][wseg] = pw0;
      *(uint4*)&ws[wk][wseg + 8] = pw1;
#pragma unroll
      for (int i = 0; i < 4; ++i) {
        uint4 o;
        o.x = pk2(px[0][i], px[1][i]);
        o.y = pk2(px[2][i], px[3][i]);
        o.z = pk2(px[4][i], px[5][i]);
        o.w = pk2(px[6][i], px[7][i]);
        *(uint4*)&xt[((size_t)n * 512 + dc + c4 + i) * 1024 + hwbase + q8] = o;
      }
      __syncthreads();
      if (c < 7) {
        const int dn = (c + 1) * 64;
#pragma unroll
        for (int j = 0; j < 8; ++j)
          px[j] = *(const float4*)&x[(size_t)(p0 + q8 + j) * 512 + dn + c4];
        pw0 = *(const uint4*)&wt[(size_t)wk * 512 + dn + wseg];
        pw1 = *(const uint4*)&wt[(size_t)wk * 512 + dn + wseg + 8];
      }
#pragma unroll
      for (int s = 0; s < 4; ++s) {
        int kd = s * 16 + h * 8;
        bf16x8 ax = *(const bf16x8*)&xs[32 * w + l31][kd];
        bf16x8 b0 = *(const bf16x8*)&ws[l31][kd];
        bf16x8 b1 = *(const bf16x8*)&ws[32 + l31][kd];
        acc0 = __builtin_amdgcn_mfma_f32_32x32x16_bf16(ax, b0, acc0, 0, 0, 0);
        acc1 = __builtin_amdgcn_mfma_f32_32x32x16_bf16(ax, b1, acc1, 0, 0, 0);
      }
    }

    const float bias0 = b[l31], bias1 = b[32 + l31];
    float a0[16], a1[16];
    float sum0 = 0.f, sum1 = 0.f;
#pragma unroll
    for (int r = 0; r < 16; ++r) {
      float s0 = acc0[r] + bias0, s1 = acc1[r] + bias1;
      float m = fmaxf(s0, s1);
#pragma unroll
      for (int msk = 1; msk < 32; msk <<= 1) m = fmaxf(m, __shfl_xor(m, msk, 64));
      float e0 = __expf(s0 - m), e1 = __expf(s1 - m);
      float S = e0 + e1;
#pragma unroll
      for (int msk = 1; msk < 32; msk <<= 1) S += __shfl_xor(S, msk, 64);
      float inv = 1.0f / S;
      a0[r] = e0 * inv; a1[r] = e1 * inv;
      sum0 += a0[r]; sum1 += a1[r];
    }
    const int hwb = hwbase + 32 * w + 4 * h;
    const size_t kb0 = ((size_t)n * 64 + l31) * 1024;
    const size_t kb1 = ((size_t)n * 64 + 32 + l31) * 1024;
#pragma unroll
    for (int g = 0; g < 4; ++g) {
      int hw = hwb + 8 * g;
      uint2 u;
      u.x = pk2(a0[4 * g + 0], a0[4 * g + 1]);
      u.y = pk2(a0[4 * g + 2], a0[4 * g + 3]);
      *(uint2*)&at[kb0 + hw] = u;
      u.x = pk2(a1[4 * g + 0], a1[4 * g + 1]);
      u.y = pk2(a1[4 * g + 2], a1[4 * g + 3]);
      *(uint2*)&at[kb1 + hw] = u;
    }
    sum0 += __shfl_xor(sum0, 32, 64);
    sum1 += __shfl_xor(sum1, 32, 64);
    if (lane < 32) {
      atomicAdd(&a_sum[n * 64 + l31], sum0);
      atomicAdd(&a_sum[n * 64 + 32 + l31], sum1);
    }
  }
  grid.sync();

  // ---------------- PB: v = xt @ at^T + a_sum*C -> out, atomic ssq ---------
  {
    unsigned short (*xa)[136] = (unsigned short(*)[136])smem;          // [d][128hw]
    unsigned short (*as_)[136] = (unsigned short(*)[136])(smem + 64 * 136 * 2);
    const int n = bid >> 3, d0 = (bid & 7) * 64;
    const int dw = 32 * (w & 1), kw = 32 * (w >> 1);
    const int sd = t >> 2, sseg = (t & 3) * 32;  // 4 thr/row, 32 shorts each
    const size_t xbase = ((size_t)n * 512 + d0 + sd) * 1024;
    const size_t abase = ((size_t)n * 64 + sd) * 1024;

    uint4 px0, px1, px2, px3, pa0, pa1, pa2, pa3;
    px0 = *(const uint4*)&xt[xbase + sseg];
    px1 = *(const uint4*)&xt[xbase + sseg + 8];
    px2 = *(const uint4*)&xt[xbase + sseg + 16];
    px3 = *(const uint4*)&xt[xbase + sseg + 24];
    pa0 = *(const uint4*)&at[abase + sseg];
    pa1 = *(const uint4*)&at[abase + sseg + 8];
    pa2 = *(const uint4*)&at[abase + sseg + 16];
    pa3 = *(const uint4*)&at[abase + sseg + 24];

    f32x16 acc;
#pragma unroll
    for (int i = 0; i < 16; ++i) acc[i] = 0.f;

    for (int c = 0; c < 8; ++c) {
      __syncthreads();
      *(uint4*)&xa[sd][sseg] = px0;
      *(uint4*)&xa[sd][sseg + 8] = px1;
      *(uint4*)&xa[sd][sseg + 16] = px2;
      *(uint4*)&xa[sd][sseg + 24] = px3;
      *(uint4*)&as_[sd][sseg] = pa0;
      *(uint4*)&as_[sd][sseg + 8] = pa1;
      *(uint4*)&as_[sd][sseg + 16] = pa2;
      *(uint4*)&as_[sd][sseg + 24] = pa3;
      __syncthreads();
      if (c < 7) {
        const int hw0 = (c + 1) * 128;
        px0 = *(const uint4*)&xt[xbase + hw0 + sseg];
        px1 = *(const uint4*)&xt[xbase + hw0 + sseg + 8];
        px2 = *(const uint4*)&xt[xbase + hw0 + sseg + 16];
        px3 = *(const uint4*)&xt[xbase + hw0 + sseg + 24];
        pa0 = *(const uint4*)&at[abase + hw0 + sseg];
        pa1 = *(const uint4*)&at[abase + hw0 + sseg + 8];
        pa2 = *(const uint4*)&at[abase + hw0 + sseg + 16];
        pa3 = *(const uint4*)&at[abase + hw0 + sseg + 24];
      }
#pragma unroll
      for (int s = 0; s < 8; ++s) {
        int kk = s * 16 + h * 8;
        bf16x8 ax = *(const bf16x8*)&xa[dw + l31][kk];
        bf16x8 bb = *(const bf16x8*)&as_[kw + l31][kk];
        acc = __builtin_amdgcn_mfma_f32_32x32x16_bf16(ax, bb, acc, 0, 0, 0);
      }
    }

    const int k = kw + l31;
    const float as = a_sum[n * 64 + k];
    float sq = 0.f;
#pragma unroll
    for (int r = 0; r < 16; ++r) {
      int row = (r & 3) + 8 * (r >> 2) + 4 * h;
      int d = d0 + dw + row;
      float o = acc[r] + as * C[(size_t)d * 64 + k];
      out[((size_t)n * 512 + d) * 64 + k] = o;
      sq += o * o;
    }
    atomicAdd(&ssq[n * 64 + k], sq);
  }
  grid.sync();

  // ---------------- PC: scale in place ----------------
  {
    const int n = bid >> 3, slice = bid & 7;
    const int k = t & 63, rg = t >> 6;
    float* sk = (float*)smem;
    float* tot = sk + 64;
    if (t < 64) {
      float c = ssq[n * 64 + t];
      sk[t] = rsqrtf(c + EPSF);
      float contrib = c / (c + EPSF);
#pragma unroll
      for (int m = 32; m; m >>= 1) contrib += __shfl_xor(contrib, m, 64);
      if (t == 0) *tot = rsqrtf(contrib + EPSF);
    }
    __syncthreads();
    const float scale = sk[k] * (*tot);
    float* vb = out + (size_t)n * 32768 + (size_t)slice * 4096;
#pragma unroll
    for (int r = rg; r < 64; r += 4) vb[r * 64 + k] *= scale;
  }
}

extern "C" void kernel_launch(void* const* d_in, const int* in_sizes, int n_in,
                              void* d_out, int out_size, void* d_ws, size_t ws_size,
                              hipStream_t stream) {
  const float* x  = (const float*)d_in[0];   // [64,32,32,512]
  const float* Wm = (const float*)d_in[1];   // [512,64]
  const float* b  = (const float*)d_in[2];   // [64]
  const float* C  = (const float*)d_in[3];   // [512,64]
  float* out = (float*)d_out;                // [64, 32768]

  unsigned short* at = (unsigned short*)d_ws;          // 8 MiB  [n*64+k][1024]
  unsigned short* xt = at + (size_t)64 * 64 * 1024;    // 64 MiB [n][512 d][1024 hw]
  unsigned short* wt = xt + (size_t)64 * 512 * 1024;   // 64 KiB [k][512 d]
  float* a_sum = (float*)(wt + (size_t)64 * 512);      // 16 KiB
  float* ssq   = a_sum + 4096;                         // 16 KiB (contiguous after a_sum)

  void* args[] = {(void*)&x, (void*)&Wm, (void*)&b, (void*)&C, (void*)&out,
                  (void*)&at, (void*)&xt, (void*)&wt, (void*)&a_sum, (void*)&ssq};
  hipLaunchCooperativeKernel((const void*)mega, dim3(512), dim3(256), args, 0, stream);
}

// Round 7
// 245.514 us; speedup vs baseline: 1.7157x; 1.7157x over previous
//
#include <hip/hip_runtime.h>

// NetVLAD fp32, N=64 HW=1024 D=512 K=64. bf16 MFMA.
// R7: barrier-free, LDS-free GEMMs. Each wave loads A/B fragments directly
// from global into registers in MFMA layout; no __syncthreads -> no
// vmcnt(0) drains -> loads stay in flight across the whole K-loop.
//   kprep:   W[512][64] -> wt[64 k][512 d] bf16; zero a_sum/ssq.
//   kassign: s = x@W+b, softmax -> at[n*64+k][1024 hw] bf16, a_sum (atomic).
//   kvlad:   v = sum_hw x[hw][d]*a[hw][k] + a_sum*C -> out, atomic ssq.
//   kscale:  intra-norm (per n,k over d) x global L2 (per n), in place.

#define EPSF 1e-12f

typedef short bf16x8 __attribute__((ext_vector_type(8)));
typedef float f32x16 __attribute__((ext_vector_type(16)));

__device__ inline unsigned short f2bf_rne(float f) {
  union { float f; unsigned u; } v; v.f = f;
  unsigned u = v.u;
  unsigned r = u + 0x7fffu + ((u >> 16) & 1u);
  return (unsigned short)(r >> 16);
}
__device__ inline unsigned pk2(float a, float b) {
#if __has_builtin(__builtin_amdgcn_cvt_pk_bf16_f32)
  auto r = __builtin_amdgcn_cvt_pk_bf16_f32(a, b);
  return __builtin_bit_cast(unsigned, r);
#else
  return (unsigned)f2bf_rne(a) | ((unsigned)f2bf_rne(b) << 16);
#endif
}
__device__ inline bf16x8 pack8(float4 lo, float4 hi) {
  union { unsigned u[4]; bf16x8 v; } r;
  r.u[0] = pk2(lo.x, lo.y);
  r.u[1] = pk2(lo.z, lo.w);
  r.u[2] = pk2(hi.x, hi.y);
  r.u[3] = pk2(hi.z, hi.w);
  return r.v;
}

// ---------------- K0: W transpose (blocks 0-7) + zero stats (block 8) ------
__global__ __launch_bounds__(256) void kprep(
    const float* __restrict__ Wm, unsigned short* __restrict__ wt,
    float* __restrict__ stats /* a_sum(4096) + ssq(4096) */) {
  const int t = threadIdx.x, bx = blockIdx.x;
  if (bx == 8) {
    float4 z = {0.f, 0.f, 0.f, 0.f};
#pragma unroll
    for (int r = 0; r < 8; ++r)
      *(float4*)&stats[(size_t)(r * 256 + t) * 4] = z;
    return;
  }
  __shared__ float tile[64][65];
  {
    int col = (t & 15) * 4, rbase = t >> 4;
#pragma unroll
    for (int r = 0; r < 4; ++r) {
      int row = rbase + 16 * r;
      *(float4*)&tile[row][col] =
          *(const float4*)&Wm[(size_t)(bx * 64 + row) * 64 + col];
    }
  }
  __syncthreads();
  int k = t >> 2, seg = (t & 3) * 16;
  size_t o = (size_t)k * 512 + bx * 64 + seg;
#pragma unroll
  for (int j = 0; j < 16; j += 2)
    *(unsigned*)&wt[o + j] = pk2(tile[seg + j][k], tile[seg + j + 1][k]);
}

// ---------------- Kernel A: assign GEMM + softmax -> at, a_sum -------------
// 512 blocks x 256 thr (4 independent waves). Wave: 32 pixels x 64 K.
// A-frag: lane l31 = pixel, 8 consecutive d from x (fp32->bf16 in regs).
// B-frag: lane l31 = k-row (and 32+l31), 16B contiguous from wt.
__global__ __launch_bounds__(256) void kassign(
    const float* __restrict__ x, const unsigned short* __restrict__ wt,
    const float* __restrict__ b, unsigned short* __restrict__ at,
    float* __restrict__ a_sum) {
  const int t = threadIdx.x;
  const int w = t >> 6, lane = t & 63, l31 = lane & 31, h = lane >> 5;
  const int bx = blockIdx.x;
  const int n = bx >> 3;                    // 8 blocks per image
  const int hwbase = (bx & 7) * 128 + 32 * w;
  const size_t prow = (size_t)(bx * 128 + 32 * w + l31) * 512;  // my pixel row
  const unsigned short* w0 = wt + (size_t)l31 * 512;
  const unsigned short* w1 = wt + (size_t)(32 + l31) * 512;

  f32x16 acc0, acc1;
#pragma unroll
  for (int i = 0; i < 16; ++i) { acc0[i] = 0.f; acc1[i] = 0.f; }

  // 32 flat steps over D (k-dim of the GEMM): kd = 16*step + 8*h
#pragma unroll 8
  for (int st = 0; st < 32; ++st) {
    const int kd = st * 16 + h * 8;
    float4 xa = *(const float4*)&x[prow + kd];
    float4 xb = *(const float4*)&x[prow + kd + 4];
    bf16x8 ax = pack8(xa, xb);
    bf16x8 b0 = *(const bf16x8*)&w0[kd];
    bf16x8 b1 = *(const bf16x8*)&w1[kd];
    acc0 = __builtin_amdgcn_mfma_f32_32x32x16_bf16(ax, b0, acc0, 0, 0, 0);
    acc1 = __builtin_amdgcn_mfma_f32_32x32x16_bf16(ax, b1, acc1, 0, 0, 0);
  }

  // softmax over k (lane dim: 32 lanes x {acc0,acc1}), emit at + a_sum
  const float bias0 = b[l31], bias1 = b[32 + l31];
  float a0[16], a1[16];
  float sum0 = 0.f, sum1 = 0.f;
#pragma unroll
  for (int r = 0; r < 16; ++r) {
    float s0 = acc0[r] + bias0, s1 = acc1[r] + bias1;
    float m = fmaxf(s0, s1);
#pragma unroll
    for (int msk = 1; msk < 32; msk <<= 1) m = fmaxf(m, __shfl_xor(m, msk, 64));
    float e0 = __expf(s0 - m), e1 = __expf(s1 - m);
    float S = e0 + e1;
#pragma unroll
    for (int msk = 1; msk < 32; msk <<= 1) S += __shfl_xor(S, msk, 64);
    float inv = 1.0f / S;
    a0[r] = e0 * inv; a1[r] = e1 * inv;
    sum0 += a0[r]; sum1 += a1[r];
  }
  const int hwb = hwbase + 4 * h;
  const size_t kb0 = ((size_t)n * 64 + l31) * 1024;
  const size_t kb1 = ((size_t)n * 64 + 32 + l31) * 1024;
#pragma unroll
  for (int g = 0; g < 4; ++g) {
    int hw = hwb + 8 * g;
    uint2 u;
    u.x = pk2(a0[4 * g + 0], a0[4 * g + 1]);
    u.y = pk2(a0[4 * g + 2], a0[4 * g + 3]);
    *(uint2*)&at[kb0 + hw] = u;
    u.x = pk2(a1[4 * g + 0], a1[4 * g + 1]);
    u.y = pk2(a1[4 * g + 2], a1[4 * g + 3]);
    *(uint2*)&at[kb1 + hw] = u;
  }
  sum0 += __shfl_xor(sum0, 32, 64);
  sum1 += __shfl_xor(sum1, 32, 64);
  if (lane < 32) {
    atomicAdd(&a_sum[n * 64 + l31], sum0);
    atomicAdd(&a_sum[n * 64 + 32 + l31], sum1);
  }
}

// ---------------- Kernel B: v = x^T @ a + a_sum*C -> out, atomic ssq -------
// grid (8, 64) x 256 thr (4 waves). Wave: 32 d x 32 k, full hw=1024.
// A-frag: lane l31 = d-row; 8 hw values gathered as coalesced dword loads
// (lanes are d-consecutive -> 128B/instr). B-frag: 16B contiguous from at.
__global__ __launch_bounds__(256) void kvlad(
    const float* __restrict__ x, const unsigned short* __restrict__ at,
    const float* __restrict__ a_sum, const float* __restrict__ C,
    float* __restrict__ out, float* __restrict__ ssq) {
  const int t = threadIdx.x;
  const int w = t >> 6, lane = t & 63, l31 = lane & 31, h = lane >> 5;
  const int n = blockIdx.y, d0 = blockIdx.x * 64;
  const int dw = 32 * (w & 1), kw = 32 * (w >> 1);
  const int d = d0 + dw + l31;
  const float* xl = x + (size_t)n * 524288 + d;                 // [hw][512]
  const unsigned short* al = at + ((size_t)n * 64 + kw + l31) * 1024;

  f32x16 acc;
#pragma unroll
  for (int i = 0; i < 16; ++i) acc[i] = 0.f;

#pragma unroll 4
  for (int m = 0; m < 64; ++m) {
    const int hwb = m * 16 + h * 8;
    float a[8];
#pragma unroll
    for (int j = 0; j < 8; ++j) a[j] = xl[(size_t)(hwb + j) * 512];
    union { unsigned u[4]; bf16x8 v; } ax;
    ax.u[0] = pk2(a[0], a[1]);
    ax.u[1] = pk2(a[2], a[3]);
    ax.u[2] = pk2(a[4], a[5]);
    ax.u[3] = pk2(a[6], a[7]);
    bf16x8 bb = *(const bf16x8*)&al[hwb];
    acc = __builtin_amdgcn_mfma_f32_32x32x16_bf16(ax.v, bb, acc, 0, 0, 0);
  }

  const int k = kw + l31;
  const float as = a_sum[n * 64 + k];
  float sq = 0.f;
#pragma unroll
  for (int r = 0; r < 16; ++r) {
    int row = (r & 3) + 8 * (r >> 2) + 4 * h;
    int dd = d0 + dw + row;
    float o = acc[r] + as * C[(size_t)dd * 64 + k];
    out[((size_t)n * 512 + dd) * 64 + k] = o;
    sq += o * o;
  }
  atomicAdd(&ssq[n * 64 + k], sq);
}

// ---------------- C: scale in place ----------------
__global__ __launch_bounds__(256) void kscale(
    float* __restrict__ out, const float* __restrict__ ssq) {
  const int n = blockIdx.y, slice = blockIdx.x;
  const int t = threadIdx.x, k = t & 63, rg = t >> 6;
  __shared__ float sk[64];
  __shared__ float tot;
  if (t < 64) {
    float c = ssq[n * 64 + t];
    sk[t] = rsqrtf(c + EPSF);
    float contrib = c / (c + EPSF);
#pragma unroll
    for (int m = 32; m; m >>= 1) contrib += __shfl_xor(contrib, m, 64);
    if (t == 0) tot = rsqrtf(contrib + EPSF);
  }
  __syncthreads();
  const float scale = sk[k] * tot;
  float* vb = out + (size_t)n * 32768 + (size_t)slice * 4096;
#pragma unroll
  for (int r = rg; r < 64; r += 4) vb[r * 64 + k] *= scale;
}

extern "C" void kernel_launch(void* const* d_in, const int* in_sizes, int n_in,
                              void* d_out, int out_size, void* d_ws, size_t ws_size,
                              hipStream_t stream) {
  const float* x  = (const float*)d_in[0];   // [64,32,32,512]
  const float* Wm = (const float*)d_in[1];   // [512,64]
  const float* b  = (const float*)d_in[2];   // [64]
  const float* C  = (const float*)d_in[3];   // [512,64]
  float* out = (float*)d_out;                // [64, 32768]

  unsigned short* at = (unsigned short*)d_ws;          // 8 MiB  [n*64+k][1024]
  unsigned short* wt = at + (size_t)64 * 64 * 1024;    // 64 KiB [k][512 d]
  float* stats = (float*)(wt + (size_t)64 * 512);      // a_sum 4096 + ssq 4096
  float* a_sum = stats;
  float* ssq   = stats + 4096;

  kprep<<<dim3(9), dim3(256), 0, stream>>>(Wm, wt, stats);
  kassign<<<dim3(512), dim3(256), 0, stream>>>(x, wt, b, at, a_sum);
  kvlad<<<dim3(8, 64), dim3(256), 0, stream>>>(x, at, a_sum, C, out, ssq);
  kscale<<<dim3(8, 64), dim3(256), 0, stream>>>(out, ssq);
}